// Round 4
// baseline (1050.760 us; speedup 1.0000x reference)
//
#include <hip/hip_runtime.h>
#include <hip/hip_bf16.h>
#include <hip/hip_cooperative_groups.h>

namespace cg = cooperative_groups;

#define DEPTH 16
#define NBLK 512

typedef __attribute__((ext_vector_type(8))) short s8v;   // 8 x bf16
typedef __attribute__((ext_vector_type(4))) float f32x4; // MFMA acc

__device__ __forceinline__ float sigf(float x) { return 1.0f / (1.0f + __expf(-x)); }
__device__ __forceinline__ float tanh_fast(float x) { return 1.0f - 2.0f / (1.0f + __expf(2.0f * x)); }
__device__ __forceinline__ ushort f2bf(float f) {
    union { __hip_bfloat16 b; ushort u; } v; v.b = __float2bfloat16(f); return v.u;
}
__device__ __forceinline__ float bf2f(ushort u) {
    union { float f; unsigned int i; } v; v.i = ((unsigned int)u) << 16; return v.f;
}

// One 64(M) x 128(N-of-512) output tile of a level GEMM + LSTM cell epilogue.
// A[m][k]: k<128 -> emb[node_types[start+m]] (with node_args patch at k=127),
//          k in [128,384) -> h_in[2m], h_in[2m+1].
// B: Bpack fragment-packed effective weights (col nl = g*32+jj within bn).
__device__ __forceinline__ void do_tile(
    int m0, int bn, int start, int n_l, bool has_h,
    const int* __restrict__ nt, const float* __restrict__ na,
    const float* __restrict__ emb,
    const ushort* __restrict__ Bpack, const float* __restrict__ bsum,
    const ushort* __restrict__ h_in, const float* __restrict__ c_in,
    ushort* __restrict__ h_out, float* __restrict__ c_out,
    float (*Gs)[128])
{
    const int tid  = threadIdx.x;
    const int lane = tid & 63;
    const int wave = tid >> 6;
    const int wm = wave >> 1, wn = wave & 1;
    const int lc = lane & 15, seg = lane >> 4;
    const int koff = seg * 8;

    int tty[2]; float targ[2];
    const ushort* ph[2][2];
    #pragma unroll
    for (int mi = 0; mi < 2; ++mi) {
        int m = m0 + wm * 32 + mi * 16 + lc;
        int mc = m < n_l ? m : n_l - 1;
        tty[mi]  = nt[start + mc];
        targ[mi] = na[start + mc];
        ph[mi][0] = h_in + (size_t)(2 * mc) * 128 + koff;
        ph[mi][1] = h_in + (size_t)(2 * mc + 1) * 128 + koff;
    }
    const ushort* pb = Bpack + (size_t)bn * 49152 + (size_t)seg * 1024
                             + (size_t)(wn * 64 + lc) * 8;

    f32x4 acc[2][4];
    #pragma unroll
    for (int mi = 0; mi < 2; ++mi)
        #pragma unroll
        for (int f = 0; f < 4; ++f) acc[mi][f] = (f32x4){0.f, 0.f, 0.f, 0.f};

    // K part 1: embedding (k = 0..127), gathered + converted inline
    #pragma unroll
    for (int kk = 0; kk < 4; ++kk) {
        s8v a[2];
        #pragma unroll
        for (int mi = 0; mi < 2; ++mi) {
            const float* src = emb + (size_t)tty[mi] * 128 + kk * 32 + koff;
            float4 w0 = *(const float4*)src;
            float4 w1 = *(const float4*)(src + 4);
            ushort o[8] = { f2bf(w0.x), f2bf(w0.y), f2bf(w0.z), f2bf(w0.w),
                            f2bf(w1.x), f2bf(w1.y), f2bf(w1.z), f2bf(w1.w) };
            if (kk == 3 && seg == 3 && (tty[mi] == 1 || tty[mi] == 2))
                o[7] = f2bf(targ[mi]);
            a[mi] = *(const s8v*)o;
        }
        #pragma unroll
        for (int f = 0; f < 4; ++f) {
            s8v b = *(const s8v*)(pb + (size_t)kk * 4096 + f * 128);
            acc[0][f] = __builtin_amdgcn_mfma_f32_16x16x32_bf16(a[0], b, acc[0][f], 0, 0, 0);
            acc[1][f] = __builtin_amdgcn_mfma_f32_16x16x32_bf16(a[1], b, acc[1][f], 0, 0, 0);
        }
    }
    // K part 2: children h (k = 128..383)
    if (has_h) {
        #pragma unroll
        for (int kk = 0; kk < 8; ++kk) {
            const int hi = kk >> 2, off = (kk & 3) * 32;
            s8v a0 = *(const s8v*)(ph[0][hi] + off);
            s8v a1 = *(const s8v*)(ph[1][hi] + off);
            #pragma unroll
            for (int f = 0; f < 4; ++f) {
                s8v b = *(const s8v*)(pb + (size_t)(kk + 4) * 4096 + f * 128);
                acc[0][f] = __builtin_amdgcn_mfma_f32_16x16x32_bf16(a0, b, acc[0][f], 0, 0, 0);
                acc[1][f] = __builtin_amdgcn_mfma_f32_16x16x32_bf16(a1, b, acc[1][f], 0, 0, 0);
            }
        }
    }

    // gates -> LDS  (D row = seg*4+r, col = lane&15)
    #pragma unroll
    for (int mi = 0; mi < 2; ++mi)
        #pragma unroll
        for (int f = 0; f < 4; ++f)
            #pragma unroll
            for (int r = 0; r < 4; ++r)
                Gs[wm * 32 + mi * 16 + seg * 4 + r][wn * 64 + f * 16 + lc] = acc[mi][f][r];
    __syncthreads();

    // LSTM cell epilogue
    #pragma unroll
    for (int q = 0; q < 8; ++q) {
        const int p = tid + 256 * q;
        const int m_local = p >> 5;
        const int jj = p & 31;
        const int m = m0 + m_local;
        if (m < n_l) {
            const int j = bn * 32 + jj;
            const float gi = Gs[m_local][jj]      + bsum[j];
            const float gf = Gs[m_local][32 + jj] + bsum[128 + j];
            const float gg = Gs[m_local][64 + jj] + bsum[256 + j];
            const float go = Gs[m_local][96 + jj] + bsum[384 + j];
            const float c0 = has_h ? c_in[(size_t)m * 128 + j] : 0.0f;
            const float cn = sigf(gf) * c0 + sigf(gi) * tanh_fast(gg);
            const float hn = sigf(go) * tanh_fast(cn);
            h_out[(size_t)m * 128 + j] = f2bf(hn);
            if (!(m & 1)) c_out[(size_t)(m >> 1) * 128 + j] = cn;
        }
    }
    __syncthreads();
}

__global__ __launch_bounds__(256, 2) void fused_tree_lstm(
    const int* __restrict__ nt, const float* __restrict__ na,
    const float* __restrict__ emb,
    const float* __restrict__ Wih, const float* __restrict__ Whh,
    const float* __restrict__ bih, const float* __restrict__ bhh,
    const float* __restrict__ W1, const float* __restrict__ b1,
    const float* __restrict__ W2, const float* __restrict__ b2,
    const float* __restrict__ vmask,
    ushort* __restrict__ Bpack, float* __restrict__ bsum,
    ushort* __restrict__ hA, ushort* __restrict__ hB,
    float* __restrict__ cA, float* __restrict__ cB,
    float* __restrict__ out)
{
    cg::grid_group gg = cg::this_grid();
    __shared__ __align__(16) float Gs[64][128];
    const int tid = threadIdx.x;

    // ---- phase 0: pack effective weights (bf16, fragment layout) + fused bias
    {
        const int gid = blockIdx.x * 256 + tid;
        if (gid < 24576) {
            const int nl  = gid & 127;
            const int seg = (gid >> 7) & 3;
            const int rest = gid >> 9;
            const int kk = rest % 12;
            const int bn = rest / 12;
            const int g  = nl >> 5;
            const int j  = bn * 32 + (nl & 31);
            const int row = g * 256 + j;
            const int k = kk * 32 + seg * 8;
            const float* src = (k < 128) ? (Wih + (size_t)row * 128 + k)
                                         : (Whh + (size_t)row * 256 + (k - 128));
            float4 w0 = *(const float4*)(src);
            float4 w1 = *(const float4*)(src + 4);
            ushort o[8] = { f2bf(w0.x), f2bf(w0.y), f2bf(w0.z), f2bf(w0.w),
                            f2bf(w1.x), f2bf(w1.y), f2bf(w1.z), f2bf(w1.w) };
            *(s8v*)(Bpack + (size_t)gid * 8) = *(const s8v*)o;
        }
        if (gid < 512) {
            const int row = (gid >> 7) * 256 + (gid & 127);
            bsum[gid] = bih[row] + bhh[row];
        }
    }
    gg.sync();

    // ---- phases 1..16: levels
    const ushort* h_prev = hB;   // dummy at leaf (never read)
    const float*  c_prev = cB;
    for (int lvl = DEPTH - 1; lvl >= 0; --lvl) {
        const int n_l = 1 << lvl;
        const int start = n_l - 1;
        const int pi = (DEPTH - 1 - lvl) & 1;
        ushort* ho = pi ? hB : hA;
        float*  co = pi ? cB : cA;
        const bool has_h = (lvl != DEPTH - 1);
        const int ntiles = ((n_l + 63) >> 6) * 4;
        for (int t = blockIdx.x; t < ntiles; t += gridDim.x)
            do_tile((t >> 2) * 64, t & 3, start, n_l, has_h,
                    nt, na, emb, Bpack, bsum, h_prev, c_prev, ho, co, Gs);
        gg.sync();
        h_prev = ho; c_prev = co;
    }

    // ---- head on block 0
    if (blockIdx.x == 0) {
        float* hs = &Gs[0][0];
        float* as = &Gs[1][0];
        if (tid < 128) hs[tid] = bf2f(h_prev[tid]);
        __syncthreads();
        if (tid < 128) {
            float acc = b1[tid];
            #pragma unroll 4
            for (int k = 0; k < 128; ++k) acc = fmaf(hs[k], W1[tid * 128 + k], acc);
            as[tid] = fmaxf(acc, 0.0f);
        }
        __syncthreads();
        if (tid < 32) {
            float l = b2[tid];
            #pragma unroll 4
            for (int k = 0; k < 128; ++k) l = fmaf(as[k], W2[tid * 128 + k], l);
            l = (l + logf(vmask[tid])) * (1.0f / 3.0f);
            float mx = l;
            #pragma unroll
            for (int o = 16; o >= 1; o >>= 1) mx = fmaxf(mx, __shfl_xor(mx, o, 32));
            const float e = __expf(l - mx);
            float s = e;
            #pragma unroll
            for (int o = 16; o >= 1; o >>= 1) s += __shfl_xor(s, o, 32);
            out[tid] = e / s;
        }
    }
}

extern "C" void kernel_launch(void* const* d_in, const int* in_sizes, int n_in,
                              void* d_out, int out_size, void* d_ws, size_t ws_size,
                              hipStream_t stream)
{
    const int*   node_types = (const int*)  d_in[0];
    const float* node_args  = (const float*)d_in[1];
    const float* vmask      = (const float*)d_in[2];
    const float* emb        = (const float*)d_in[3];
    const float* Wih        = (const float*)d_in[4];
    const float* Whh        = (const float*)d_in[5];
    const float* bih        = (const float*)d_in[6];
    const float* bhh        = (const float*)d_in[7];
    const float* W1         = (const float*)d_in[8];
    const float* b1         = (const float*)d_in[9];
    const float* W2         = (const float*)d_in[10];
    const float* b2         = (const float*)d_in[11];

    char* w = (char*)d_ws;
    ushort* Bpack = (ushort*)(w);                 // 24576*8*2   =   393,216
    float*  bsum  = (float*) (w + 393216);        // 512*4       =     2,048
    ushort* hA    = (ushort*)(w + 395264);        // 32768*128*2 = 8,388,608
    ushort* hB    = (ushort*)(w + 8783872);       // 16384*128*2 = 4,194,304
    float*  cA    = (float*) (w + 12978176);      // 16384*128*4 = 8,388,608
    float*  cB    = (float*) (w + 21366784);      // 8192*128*4  = 4,194,304

    float* out = (float*)d_out;

    void* args[] = {
        (void*)&node_types, (void*)&node_args, (void*)&emb,
        (void*)&Wih, (void*)&Whh, (void*)&bih, (void*)&bhh,
        (void*)&W1, (void*)&b1, (void*)&W2, (void*)&b2, (void*)&vmask,
        (void*)&Bpack, (void*)&bsum, (void*)&hA, (void*)&hB,
        (void*)&cA, (void*)&cB, (void*)&out
    };
    hipLaunchCooperativeKernel((void*)fused_tree_lstm, dim3(NBLK), dim3(256),
                               args, 0, stream);
}

// Round 5
// 273.460 us; speedup vs baseline: 3.8425x; 3.8425x over previous
//
#include <hip/hip_runtime.h>
#include <hip/hip_bf16.h>

#define DEPTH 16

typedef __attribute__((ext_vector_type(8))) short s8v;   // 8 x bf16
typedef __attribute__((ext_vector_type(4))) float f32x4; // MFMA acc

__device__ __forceinline__ float sigf(float x) { return 1.0f / (1.0f + __expf(-x)); }
__device__ __forceinline__ float tanh_fast(float x) { return 1.0f - 2.0f / (1.0f + __expf(2.0f * x)); }
__device__ __forceinline__ ushort f2bf(float f) {
    union { __hip_bfloat16 b; ushort u; } v; v.b = __float2bfloat16(f); return v.u;
}

// ---------------- prepass: pack effective weights + fused bias ----------------
// Bpack element layout: (((bn*12 + kk)*4 + seg)*128 + nl)*8 + t
// NEW col order within a bn block: nl -> gate g=(nl>>4)&3, j = bn*32 + (nl>>6)*16 + (nl&15)
// so that after MFMA each lane holds all 4 gates for ONE j (register-only epilogue).
__global__ __launch_bounds__(256) void pack_weights(
    const float* __restrict__ Wih, const float* __restrict__ Whh,
    const float* __restrict__ bih, const float* __restrict__ bhh,
    ushort* __restrict__ Bpack, float* __restrict__ bsum)
{
    const int gid = blockIdx.x * 256 + threadIdx.x;
    if (gid < 24576) {
        const int nl  = gid & 127;
        const int seg = (gid >> 7) & 3;
        const int rest = gid >> 9;
        const int kk = rest % 12;
        const int bn = rest / 12;
        const int g  = (nl >> 4) & 3;
        const int j  = bn * 32 + ((nl >> 6) << 4) + (nl & 15);
        const int row = g * 256 + j;
        const int k = kk * 32 + seg * 8;
        const float* src = (k < 128) ? (Wih + (size_t)row * 128 + k)
                                     : (Whh + (size_t)row * 256 + (k - 128));
        float4 w0 = *(const float4*)(src);
        float4 w1 = *(const float4*)(src + 4);
        ushort o[8] = { f2bf(w0.x), f2bf(w0.y), f2bf(w0.z), f2bf(w0.w),
                        f2bf(w1.x), f2bf(w1.y), f2bf(w1.z), f2bf(w1.w) };
        *(s8v*)(Bpack + (size_t)gid * 8) = *(const s8v*)o;
    }
    if (gid < 512) {  // bsum[g*128 + j]
        const int row = (gid >> 7) * 256 + (gid & 127);
        bsum[gid] = bih[row] + bhh[row];
    }
}

// ---------------- per-level GEMM + register LSTM epilogue ----------------
// Block: NMI*32 rows x 128 cols (of 512 eff). 4 waves = 2(wm) x 2(wn).
// Lane after MFMA holds, for rows {tb+seg*4+r}, j = bn*32+wn*16+lc, gates g=0..3 in acc[mi][g][r].
template<int NMI>
__global__ __launch_bounds__(256) void level_gemm(
    const int* __restrict__ nt, const float* __restrict__ na,
    const float* __restrict__ emb,
    const ushort* __restrict__ Bpack, const float* __restrict__ bsum,
    const ushort* __restrict__ h_in, const float* __restrict__ c_in,
    ushort* __restrict__ h_out, float* __restrict__ c_out,
    int start, int n_l, int has_h)
{
    const int tid  = threadIdx.x;
    const int lane = tid & 63;
    const int wave = tid >> 6;
    const int wm = wave >> 1, wn = wave & 1;
    const int lc = lane & 15, seg = lane >> 4;
    const int koff = seg * 8;
    const int bn = blockIdx.y;
    const int m0 = blockIdx.x * (NMI * 32);

    int tty[NMI]; float targ[NMI];
    const ushort* ph[NMI][2];
    #pragma unroll
    for (int mi = 0; mi < NMI; ++mi) {
        int m = m0 + wm * (NMI * 16) + mi * 16 + lc;
        int mc = m < n_l ? m : n_l - 1;
        tty[mi]  = nt[start + mc];
        targ[mi] = na[start + mc];
        ph[mi][0] = h_in + (size_t)(2 * mc) * 128 + koff;
        ph[mi][1] = h_in + (size_t)(2 * mc + 1) * 128 + koff;
    }
    const ushort* pb = Bpack + (size_t)bn * 49152 + (size_t)seg * 1024
                             + (size_t)(wn * 64 + lc) * 8;

    f32x4 acc[NMI][4];
    #pragma unroll
    for (int mi = 0; mi < NMI; ++mi)
        #pragma unroll
        for (int f = 0; f < 4; ++f) acc[mi][f] = (f32x4){0.f, 0.f, 0.f, 0.f};

    // K part 1: embedding (k = 0..127), gathered + converted inline
    #pragma unroll
    for (int kk = 0; kk < 4; ++kk) {
        s8v a[NMI];
        #pragma unroll
        for (int mi = 0; mi < NMI; ++mi) {
            const float* src = emb + (size_t)tty[mi] * 128 + kk * 32 + koff;
            float4 w0 = *(const float4*)src;
            float4 w1 = *(const float4*)(src + 4);
            ushort o[8] = { f2bf(w0.x), f2bf(w0.y), f2bf(w0.z), f2bf(w0.w),
                            f2bf(w1.x), f2bf(w1.y), f2bf(w1.z), f2bf(w1.w) };
            if (kk == 3 && seg == 3 && (tty[mi] == 1 || tty[mi] == 2))
                o[7] = f2bf(targ[mi]);
            a[mi] = *(const s8v*)o;
        }
        #pragma unroll
        for (int f = 0; f < 4; ++f) {
            s8v b = *(const s8v*)(pb + (size_t)kk * 4096 + f * 128);
            #pragma unroll
            for (int mi = 0; mi < NMI; ++mi)
                acc[mi][f] = __builtin_amdgcn_mfma_f32_16x16x32_bf16(a[mi], b, acc[mi][f], 0, 0, 0);
        }
    }
    // K part 2: children h (k = 128..383)
    if (has_h) {
        #pragma unroll
        for (int kk = 0; kk < 8; ++kk) {
            const int hi = kk >> 2, off = (kk & 3) * 32;
            s8v a[NMI];
            #pragma unroll
            for (int mi = 0; mi < NMI; ++mi) a[mi] = *(const s8v*)(ph[mi][hi] + off);
            #pragma unroll
            for (int f = 0; f < 4; ++f) {
                s8v b = *(const s8v*)(pb + (size_t)(kk + 4) * 4096 + f * 128);
                #pragma unroll
                for (int mi = 0; mi < NMI; ++mi)
                    acc[mi][f] = __builtin_amdgcn_mfma_f32_16x16x32_bf16(a[mi], b, acc[mi][f], 0, 0, 0);
            }
        }
    }

    // register-only LSTM epilogue
    const int j = bn * 32 + wn * 16 + lc;
    const float bi = bsum[j];
    const float bf = bsum[128 + j];
    const float bg = bsum[256 + j];
    const float bo = bsum[384 + j];
    #pragma unroll
    for (int mi = 0; mi < NMI; ++mi) {
        const int tb = m0 + wm * (NMI * 16) + mi * 16 + seg * 4;
        #pragma unroll
        for (int r = 0; r < 4; ++r) {
            const int m = tb + r;
            if (m < n_l) {
                const float gi = acc[mi][0][r] + bi;
                const float gf = acc[mi][1][r] + bf;
                const float gg = acc[mi][2][r] + bg;
                const float go = acc[mi][3][r] + bo;
                const float c0 = has_h ? c_in[(size_t)m * 128 + j] : 0.0f;
                const float cn = sigf(gf) * c0 + sigf(gi) * tanh_fast(gg);
                const float hn = sigf(go) * tanh_fast(cn);
                h_out[(size_t)m * 128 + j] = f2bf(hn);
                if (!(m & 1)) c_out[(size_t)(m >> 1) * 128 + j] = cn;
            }
        }
    }
}

// ---------------- root level (1 node, all 512 cols) + head, one block ----------------
__global__ __launch_bounds__(256) void root_and_head(
    const int* __restrict__ nt, const float* __restrict__ na,
    const float* __restrict__ emb,
    const ushort* __restrict__ Bpack, const float* __restrict__ bsum,
    const ushort* __restrict__ h_in, const float* __restrict__ c_in,
    const float* __restrict__ W1, const float* __restrict__ b1,
    const float* __restrict__ W2, const float* __restrict__ b2,
    const float* __restrict__ vmask, float* __restrict__ out)
{
    __shared__ float hs[128];
    __shared__ float as[128];
    const int tid  = threadIdx.x;
    const int lane = tid & 63;
    const int bn   = tid >> 6;       // wave = bn block
    const int lc = lane & 15, seg = lane >> 4;
    const int koff = seg * 8;

    const int   ty  = nt[0];
    const float arg = na[0];
    const ushort* ph0 = h_in + koff;          // left child (level-1 row 0)
    const ushort* ph1 = h_in + 128 + koff;    // right child
    const ushort* pb = Bpack + (size_t)bn * 49152 + (size_t)seg * 1024 + (size_t)lc * 8;

    f32x4 acc[8];
    #pragma unroll
    for (int f = 0; f < 8; ++f) acc[f] = (f32x4){0.f, 0.f, 0.f, 0.f};

    #pragma unroll
    for (int kk = 0; kk < 4; ++kk) {
        const float* src = emb + (size_t)ty * 128 + kk * 32 + koff;
        float4 w0 = *(const float4*)src;
        float4 w1 = *(const float4*)(src + 4);
        ushort o[8] = { f2bf(w0.x), f2bf(w0.y), f2bf(w0.z), f2bf(w0.w),
                        f2bf(w1.x), f2bf(w1.y), f2bf(w1.z), f2bf(w1.w) };
        if (kk == 3 && seg == 3 && (ty == 1 || ty == 2)) o[7] = f2bf(arg);
        s8v a = *(const s8v*)o;
        #pragma unroll
        for (int f = 0; f < 8; ++f) {
            s8v b = *(const s8v*)(pb + (size_t)kk * 4096 + f * 128);
            acc[f] = __builtin_amdgcn_mfma_f32_16x16x32_bf16(a, b, acc[f], 0, 0, 0);
        }
    }
    #pragma unroll
    for (int kk = 0; kk < 8; ++kk) {
        s8v a = *(const s8v*)(((kk >> 2) ? ph1 : ph0) + (kk & 3) * 32);
        #pragma unroll
        for (int f = 0; f < 8; ++f) {
            s8v b = *(const s8v*)(pb + (size_t)(kk + 4) * 4096 + f * 128);
            acc[f] = __builtin_amdgcn_mfma_f32_16x16x32_bf16(a, b, acc[f], 0, 0, 0);
        }
    }

    // row 0 lives in lanes seg==0, reg r=0. f = bhalf*4 + gate.
    if (seg == 0) {
        #pragma unroll
        for (int bh = 0; bh < 2; ++bh) {
            const int j = bn * 32 + bh * 16 + lc;
            const float gi = acc[bh * 4 + 0][0] + bsum[j];
            const float gf = acc[bh * 4 + 1][0] + bsum[128 + j];
            const float gg = acc[bh * 4 + 2][0] + bsum[256 + j];
            const float go = acc[bh * 4 + 3][0] + bsum[384 + j];
            const float cn = sigf(gf) * c_in[j] + sigf(gi) * tanh_fast(gg);
            hs[j] = sigf(go) * tanh_fast(cn);
        }
    }
    __syncthreads();
    if (tid < 128) {
        float a1 = b1[tid];
        #pragma unroll 4
        for (int k = 0; k < 128; ++k) a1 = fmaf(hs[k], W1[tid * 128 + k], a1);
        as[tid] = fmaxf(a1, 0.0f);
    }
    __syncthreads();
    if (tid < 32) {
        float l = b2[tid];
        #pragma unroll 4
        for (int k = 0; k < 128; ++k) l = fmaf(as[k], W2[tid * 128 + k], l);
        l = (l + logf(vmask[tid])) * (1.0f / 3.0f);
        float mx = l;
        #pragma unroll
        for (int o = 16; o >= 1; o >>= 1) mx = fmaxf(mx, __shfl_xor(mx, o, 32));
        const float e = __expf(l - mx);
        float s = e;
        #pragma unroll
        for (int o = 16; o >= 1; o >>= 1) s += __shfl_xor(s, o, 32);
        out[tid] = e / s;
    }
}

extern "C" void kernel_launch(void* const* d_in, const int* in_sizes, int n_in,
                              void* d_out, int out_size, void* d_ws, size_t ws_size,
                              hipStream_t stream)
{
    const int*   node_types = (const int*)  d_in[0];
    const float* node_args  = (const float*)d_in[1];
    const float* vmask      = (const float*)d_in[2];
    const float* emb        = (const float*)d_in[3];
    const float* Wih        = (const float*)d_in[4];
    const float* Whh        = (const float*)d_in[5];
    const float* bih        = (const float*)d_in[6];
    const float* bhh        = (const float*)d_in[7];
    const float* W1         = (const float*)d_in[8];
    const float* b1         = (const float*)d_in[9];
    const float* W2         = (const float*)d_in[10];
    const float* b2         = (const float*)d_in[11];

    char* w = (char*)d_ws;
    ushort* Bpack = (ushort*)(w);                 // 24576*8*2   =   393,216
    float*  bsum  = (float*) (w + 393216);        // 512*4       =     2,048
    ushort* hA    = (ushort*)(w + 395264);        // 32768*128*2 = 8,388,608
    ushort* hB    = (ushort*)(w + 8783872);       // 16384*128*2 = 4,194,304
    float*  cA    = (float*) (w + 12978176);      // 16384*128*4 = 8,388,608
    float*  cB    = (float*) (w + 21366784);      // 8192*128*4  = 4,194,304

    pack_weights<<<96, 256, 0, stream>>>(Wih, Whh, bih, bhh, Bpack, bsum);

    const ushort* h_prev = hB;   // dummy at leaf (never read)
    const float*  c_prev = cB;
    for (int lvl = DEPTH - 1; lvl >= 1; --lvl) {
        const int n_l = 1 << lvl;
        const int start = n_l - 1;
        const int pi = (DEPTH - 1 - lvl) & 1;
        ushort* ho = pi ? hB : hA;
        float*  co = pi ? cB : cA;
        const int has_h = (lvl != DEPTH - 1) ? 1 : 0;
        if (n_l >= 256) {
            dim3 grid(n_l / 128, 4);
            level_gemm<4><<<grid, 256, 0, stream>>>(
                node_types, node_args, emb, Bpack, bsum,
                h_prev, c_prev, ho, co, start, n_l, has_h);
        } else {
            dim3 grid((n_l + 63) / 64, 4);
            level_gemm<2><<<grid, 256, 0, stream>>>(
                node_types, node_args, emb, Bpack, bsum,
                h_prev, c_prev, ho, co, start, n_l, has_h);
        }
        h_prev = ho; c_prev = co;
    }
    // root (level 0) + head; level-1 outputs are in hA/cA (pi for lvl=1 is 0)
    root_and_head<<<1, 256, 0, stream>>>(
        node_types, node_args, emb, Bpack, bsum, h_prev, c_prev,
        W1, b1, W2, b2, vmask, (float*)d_out);
}

// Round 6
// 220.843 us; speedup vs baseline: 4.7579x; 1.2383x over previous
//
#include <hip/hip_runtime.h>
#include <hip/hip_bf16.h>

#define DEPTH 16

typedef __attribute__((ext_vector_type(8))) short s8v;   // 8 x bf16
typedef __attribute__((ext_vector_type(4))) float f32x4; // MFMA acc

__device__ __forceinline__ float sigf(float x) { return 1.0f / (1.0f + __expf(-x)); }
__device__ __forceinline__ float tanh_fast(float x) { return 1.0f - 2.0f / (1.0f + __expf(2.0f * x)); }
__device__ __forceinline__ ushort f2bf(float f) {
    union { __hip_bfloat16 b; ushort u; } v; v.b = __float2bfloat16(f); return v.u;
}
__device__ __forceinline__ float bf2f(ushort u) {
    union { float f; unsigned int i; } v; v.i = ((unsigned int)u) << 16; return v.f;
}

// ---------------- prepass: pack weights + fused bias + bf16 embedding gather ----------------
// Bpack: (((bn*12 + kk)*4 + seg)*128 + nl)*8 + t, col order nl -> g=(nl>>4)&3,
// j = bn*32 + (nl>>6)*16 + (nl&15)  => after MFMA each lane holds all 4 gates of one j.
__global__ __launch_bounds__(256) void prepass(
    const int* __restrict__ nt, const float* __restrict__ na,
    const float* __restrict__ emb,
    const float* __restrict__ Wih, const float* __restrict__ Whh,
    const float* __restrict__ bih, const float* __restrict__ bhh,
    ushort* __restrict__ Bpack, float* __restrict__ bsum,
    ushort* __restrict__ xall)
{
    const int gid = blockIdx.x * 256 + threadIdx.x;
    if (gid < 24576) {
        const int nl  = gid & 127;
        const int seg = (gid >> 7) & 3;
        const int rest = gid >> 9;
        const int kk = rest % 12;
        const int bn = rest / 12;
        const int g  = (nl >> 4) & 3;
        const int j  = bn * 32 + ((nl >> 6) << 4) + (nl & 15);
        const int row = g * 256 + j;
        const int k = kk * 32 + seg * 8;
        const float* src = (k < 128) ? (Wih + (size_t)row * 128 + k)
                                     : (Whh + (size_t)row * 256 + (k - 128));
        float4 w0 = *(const float4*)(src);
        float4 w1 = *(const float4*)(src + 4);
        ushort o[8] = { f2bf(w0.x), f2bf(w0.y), f2bf(w0.z), f2bf(w0.w),
                        f2bf(w1.x), f2bf(w1.y), f2bf(w1.z), f2bf(w1.w) };
        *(s8v*)(Bpack + (size_t)gid * 8) = *(const s8v*)o;
    }
    if (gid < 512) {
        const int row = (gid >> 7) * 256 + (gid & 127);
        bsum[gid] = bih[row] + bhh[row];
    }
    const int node = gid >> 4;
    const int run  = gid & 15;
    if (node < 65535) {
        const int ty = nt[node];
        const float* src = emb + (size_t)ty * 128 + run * 8;
        float4 w0 = *(const float4*)src;
        float4 w1 = *(const float4*)(src + 4);
        if (run == 15 && (ty == 1 || ty == 2)) w1.w = na[node];
        ushort o[8] = { f2bf(w0.x), f2bf(w0.y), f2bf(w0.z), f2bf(w0.w),
                        f2bf(w1.x), f2bf(w1.y), f2bf(w1.z), f2bf(w1.w) };
        *(s8v*)(xall + (size_t)node * 128 + run * 8) = *(const s8v*)o;
    }
}

// ---------------- single-level GEMM + register LSTM epilogue ----------------
// Block: 64 rows x 128 cols (one bn of 512 eff). 4 waves = 2(wm) x 2(wn).
__global__ __launch_bounds__(256) void level_gemm(
    const ushort* __restrict__ xall,
    const ushort* __restrict__ Bpack, const float* __restrict__ bsum,
    const ushort* __restrict__ h_in, const float* __restrict__ c_in,
    ushort* __restrict__ h_out, float* __restrict__ c_out,
    int start, int n_l, int has_h)
{
    const int tid  = threadIdx.x;
    const int lane = tid & 63;
    const int wave = tid >> 6;
    const int wm = wave >> 1, wn = wave & 1;
    const int lc = lane & 15, seg = lane >> 4;
    const int koff = seg * 8;
    const int bn = blockIdx.y;
    const int m0 = blockIdx.x * 64;

    const ushort* px[2];
    const ushort* ph[2][2];
    #pragma unroll
    for (int mi = 0; mi < 2; ++mi) {
        int m = m0 + wm * 32 + mi * 16 + lc;
        int mc = m < n_l ? m : n_l - 1;
        px[mi]    = xall + (size_t)(start + mc) * 128 + koff;
        ph[mi][0] = h_in + (size_t)(2 * mc) * 128 + koff;
        ph[mi][1] = h_in + (size_t)(2 * mc + 1) * 128 + koff;
    }
    const ushort* pb = Bpack + (size_t)bn * 49152 + (size_t)seg * 1024
                             + (size_t)(wn * 64 + lc) * 8;

    f32x4 acc[2][4];
    #pragma unroll
    for (int mi = 0; mi < 2; ++mi)
        #pragma unroll
        for (int f = 0; f < 4; ++f) acc[mi][f] = (f32x4){0.f, 0.f, 0.f, 0.f};

    #pragma unroll
    for (int kk = 0; kk < 4; ++kk) {
        s8v a0 = *(const s8v*)(px[0] + kk * 32);
        s8v a1 = *(const s8v*)(px[1] + kk * 32);
        #pragma unroll
        for (int f = 0; f < 4; ++f) {
            s8v b = *(const s8v*)(pb + (size_t)kk * 4096 + f * 128);
            acc[0][f] = __builtin_amdgcn_mfma_f32_16x16x32_bf16(a0, b, acc[0][f], 0, 0, 0);
            acc[1][f] = __builtin_amdgcn_mfma_f32_16x16x32_bf16(a1, b, acc[1][f], 0, 0, 0);
        }
    }
    if (has_h) {
        #pragma unroll
        for (int kk = 0; kk < 8; ++kk) {
            const int hi = kk >> 2, off = (kk & 3) * 32;
            s8v a0 = *(const s8v*)(ph[0][hi] + off);
            s8v a1 = *(const s8v*)(ph[1][hi] + off);
            #pragma unroll
            for (int f = 0; f < 4; ++f) {
                s8v b = *(const s8v*)(pb + (size_t)(kk + 4) * 4096 + f * 128);
                acc[0][f] = __builtin_amdgcn_mfma_f32_16x16x32_bf16(a0, b, acc[0][f], 0, 0, 0);
                acc[1][f] = __builtin_amdgcn_mfma_f32_16x16x32_bf16(a1, b, acc[1][f], 0, 0, 0);
            }
        }
    }

    const int j = bn * 32 + wn * 16 + lc;
    const float bi = bsum[j];
    const float bf = bsum[128 + j];
    const float bg = bsum[256 + j];
    const float bo = bsum[384 + j];
    #pragma unroll
    for (int mi = 0; mi < 2; ++mi) {
        const int tb = m0 + wm * 32 + mi * 16 + seg * 4;
        #pragma unroll
        for (int r = 0; r < 4; ++r) {
            const int m = tb + r;
            if (m < n_l) {
                const float gi = acc[mi][0][r] + bi;
                const float gf = acc[mi][1][r] + bf;
                const float gg = acc[mi][2][r] + bg;
                const float go = acc[mi][3][r] + bo;
                const float c0 = has_h ? c_in[(size_t)m * 128 + j] : 0.0f;
                const float cn = sigf(gf) * c0 + sigf(gi) * tanh_fast(gg);
                const float hn = sigf(go) * tanh_fast(cn);
                h_out[(size_t)m * 128 + j] = f2bf(hn);
                if (!(m & 1)) c_out[(size_t)(m >> 1) * 128 + j] = cn;
            }
        }
    }
}

// ---------------- two-level pair kernel ----------------
// Block b: parents [32b,32b+32) of level P, children [64b,64b+64) of level C=P+1
// (computed in stage 1 into LDS), grandchildren read from global (level G=P+2).
__global__ __launch_bounds__(512) void pair_gemm(
    const ushort* __restrict__ xall,
    const ushort* __restrict__ Bpack, const float* __restrict__ bsum,
    const ushort* __restrict__ h_in, const float* __restrict__ c_in,  // level G: h full, c compact
    ushort* __restrict__ h_out, float* __restrict__ c_out,            // level P: h full, c compact
    int startC, int startP, int nP)
{
    __shared__ __align__(16) ushort hC[64][136];
    __shared__ float cC[32][132];

    const int tid  = threadIdx.x;
    const int lane = tid & 63;
    const int wave = tid >> 6;
    const int lc = lane & 15, seg = lane >> 4;
    const int koff = seg * 8;
    const int nC = 2 * nP;
    const int b = blockIdx.x;

    // ===== stage 1: level C (children), M=64, N=512 =====
    {
        const int wm2 = wave >> 2;   // 0..1 : 32-row half
        const int bn  = wave & 3;
        const ushort* px[2];
        const ushort* ph[2][2];
        int cgv[2];
        #pragma unroll
        for (int mi = 0; mi < 2; ++mi) {
            int mloc = wm2 * 32 + mi * 16 + lc;
            int cg = 64 * b + mloc;
            int cgc = cg < nC ? cg : nC - 1;
            cgv[mi] = cgc;
            px[mi]    = xall + (size_t)(startC + cgc) * 128 + koff;
            ph[mi][0] = h_in + (size_t)(2 * cgc) * 128 + koff;
            ph[mi][1] = h_in + (size_t)(2 * cgc + 1) * 128 + koff;
        }
        const ushort* pb = Bpack + (size_t)bn * 49152 + (size_t)seg * 1024
                                 + (size_t)lc * 8;

        f32x4 acc[2][8];
        #pragma unroll
        for (int mi = 0; mi < 2; ++mi)
            #pragma unroll
            for (int f = 0; f < 8; ++f) acc[mi][f] = (f32x4){0.f, 0.f, 0.f, 0.f};

        #pragma unroll
        for (int kk = 0; kk < 4; ++kk) {
            s8v a0 = *(const s8v*)(px[0] + kk * 32);
            s8v a1 = *(const s8v*)(px[1] + kk * 32);
            #pragma unroll
            for (int f = 0; f < 8; ++f) {
                s8v bb = *(const s8v*)(pb + (size_t)kk * 4096 + f * 128);
                acc[0][f] = __builtin_amdgcn_mfma_f32_16x16x32_bf16(a0, bb, acc[0][f], 0, 0, 0);
                acc[1][f] = __builtin_amdgcn_mfma_f32_16x16x32_bf16(a1, bb, acc[1][f], 0, 0, 0);
            }
        }
        #pragma unroll
        for (int kk = 0; kk < 8; ++kk) {
            const int hi = kk >> 2, off = (kk & 3) * 32;
            s8v a0 = *(const s8v*)(ph[0][hi] + off);
            s8v a1 = *(const s8v*)(ph[1][hi] + off);
            #pragma unroll
            for (int f = 0; f < 8; ++f) {
                s8v bb = *(const s8v*)(pb + (size_t)(kk + 4) * 4096 + f * 128);
                acc[0][f] = __builtin_amdgcn_mfma_f32_16x16x32_bf16(a0, bb, acc[0][f], 0, 0, 0);
                acc[1][f] = __builtin_amdgcn_mfma_f32_16x16x32_bf16(a1, bb, acc[1][f], 0, 0, 0);
            }
        }
        // epilogue 1 -> LDS
        #pragma unroll
        for (int bh = 0; bh < 2; ++bh) {
            const int j = bn * 32 + bh * 16 + lc;
            const float bi = bsum[j];
            const float bf = bsum[128 + j];
            const float bg = bsum[256 + j];
            const float bo = bsum[384 + j];
            #pragma unroll
            for (int mi = 0; mi < 2; ++mi) {
                #pragma unroll
                for (int r = 0; r < 4; ++r) {
                    const int mloc = wm2 * 32 + mi * 16 + seg * 4 + r;
                    if (mloc < nC) {
                        const int cg = 64 * b + mloc;
                        const float gi = acc[mi][bh * 4 + 0][r] + bi;
                        const float gf = acc[mi][bh * 4 + 1][r] + bf;
                        const float gg = acc[mi][bh * 4 + 2][r] + bg;
                        const float go = acc[mi][bh * 4 + 3][r] + bo;
                        const float c0 = c_in[(size_t)cg * 128 + j];
                        const float cn = sigf(gf) * c0 + sigf(gi) * tanh_fast(gg);
                        const float hn = sigf(go) * tanh_fast(cn);
                        hC[mloc][j] = f2bf(hn);
                        if (!(mloc & 1)) cC[mloc >> 1][j] = cn;
                    }
                }
            }
        }
    }
    __syncthreads();

    // ===== stage 2: level P (parents), M=32, N=512 =====
    {
        const int bn = wave >> 1;
        const int wn = wave & 1;
        const ushort* px[2];
        #pragma unroll
        for (int mi = 0; mi < 2; ++mi) {
            int m = mi * 16 + lc;
            int mPg = 32 * b + m;
            int mc = mPg < nP ? mPg : nP - 1;
            px[mi] = xall + (size_t)(startP + mc) * 128 + koff;
        }
        const ushort* pb = Bpack + (size_t)bn * 49152 + (size_t)seg * 1024
                                 + (size_t)(wn * 64 + lc) * 8;

        f32x4 acc[2][4];
        #pragma unroll
        for (int mi = 0; mi < 2; ++mi)
            #pragma unroll
            for (int f = 0; f < 4; ++f) acc[mi][f] = (f32x4){0.f, 0.f, 0.f, 0.f};

        #pragma unroll
        for (int kk = 0; kk < 4; ++kk) {
            s8v a0 = *(const s8v*)(px[0] + kk * 32);
            s8v a1 = *(const s8v*)(px[1] + kk * 32);
            #pragma unroll
            for (int f = 0; f < 4; ++f) {
                s8v bb = *(const s8v*)(pb + (size_t)kk * 4096 + f * 128);
                acc[0][f] = __builtin_amdgcn_mfma_f32_16x16x32_bf16(a0, bb, acc[0][f], 0, 0, 0);
                acc[1][f] = __builtin_amdgcn_mfma_f32_16x16x32_bf16(a1, bb, acc[1][f], 0, 0, 0);
            }
        }
        #pragma unroll
        for (int kk = 0; kk < 8; ++kk) {
            const int hi = kk >> 2, off = (kk & 3) * 32;
            s8v a0 = *(const s8v*)(&hC[2 * (0 * 16 + lc) + hi][off + koff]);
            s8v a1 = *(const s8v*)(&hC[2 * (1 * 16 + lc) + hi][off + koff]);
            #pragma unroll
            for (int f = 0; f < 4; ++f) {
                s8v bb = *(const s8v*)(pb + (size_t)(kk + 4) * 4096 + f * 128);
                acc[0][f] = __builtin_amdgcn_mfma_f32_16x16x32_bf16(a0, bb, acc[0][f], 0, 0, 0);
                acc[1][f] = __builtin_amdgcn_mfma_f32_16x16x32_bf16(a1, bb, acc[1][f], 0, 0, 0);
            }
        }

        const int j = bn * 32 + wn * 16 + lc;
        const float bi = bsum[j];
        const float bf = bsum[128 + j];
        const float bg = bsum[256 + j];
        const float bo = bsum[384 + j];
        #pragma unroll
        for (int mi = 0; mi < 2; ++mi) {
            #pragma unroll
            for (int r = 0; r < 4; ++r) {
                const int m = mi * 16 + seg * 4 + r;
                const int mPg = 32 * b + m;
                if (mPg < nP) {
                    const float gi = acc[mi][0][r] + bi;
                    const float gf = acc[mi][1][r] + bf;
                    const float gg = acc[mi][2][r] + bg;
                    const float go = acc[mi][3][r] + bo;
                    const float c0 = cC[m][j];
                    const float cn = sigf(gf) * c0 + sigf(gi) * tanh_fast(gg);
                    const float hn = sigf(go) * tanh_fast(cn);
                    h_out[(size_t)mPg * 128 + j] = f2bf(hn);
                    if (!(mPg & 1)) c_out[(size_t)(mPg >> 1) * 128 + j] = cn;
                }
            }
        }
    }
}

// ---------------- root level (1 node, all 512 cols) + head ----------------
__global__ __launch_bounds__(256) void root_and_head(
    const int* __restrict__ nt, const float* __restrict__ na,
    const float* __restrict__ emb,
    const ushort* __restrict__ Bpack, const float* __restrict__ bsum,
    const ushort* __restrict__ h_in, const float* __restrict__ c_in,
    const float* __restrict__ W1, const float* __restrict__ b1,
    const float* __restrict__ W2, const float* __restrict__ b2,
    const float* __restrict__ vmask, float* __restrict__ out)
{
    __shared__ float hs[128];
    __shared__ float as[128];
    const int tid  = threadIdx.x;
    const int lane = tid & 63;
    const int bn   = tid >> 6;
    const int lc = lane & 15, seg = lane >> 4;
    const int koff = seg * 8;

    const int   ty  = nt[0];
    const float arg = na[0];
    const ushort* ph0 = h_in + koff;
    const ushort* ph1 = h_in + 128 + koff;
    const ushort* pb = Bpack + (size_t)bn * 49152 + (size_t)seg * 1024 + (size_t)lc * 8;

    f32x4 acc[8];
    #pragma unroll
    for (int f = 0; f < 8; ++f) acc[f] = (f32x4){0.f, 0.f, 0.f, 0.f};

    #pragma unroll
    for (int kk = 0; kk < 4; ++kk) {
        const float* src = emb + (size_t)ty * 128 + kk * 32 + koff;
        float4 w0 = *(const float4*)src;
        float4 w1 = *(const float4*)(src + 4);
        ushort o[8] = { f2bf(w0.x), f2bf(w0.y), f2bf(w0.z), f2bf(w0.w),
                        f2bf(w1.x), f2bf(w1.y), f2bf(w1.z), f2bf(w1.w) };
        if (kk == 3 && seg == 3 && (ty == 1 || ty == 2)) o[7] = f2bf(arg);
        s8v a = *(const s8v*)o;
        #pragma unroll
        for (int f = 0; f < 8; ++f) {
            s8v b = *(const s8v*)(pb + (size_t)kk * 4096 + f * 128);
            acc[f] = __builtin_amdgcn_mfma_f32_16x16x32_bf16(a, b, acc[f], 0, 0, 0);
        }
    }
    #pragma unroll
    for (int kk = 0; kk < 8; ++kk) {
        s8v a = *(const s8v*)(((kk >> 2) ? ph1 : ph0) + (kk & 3) * 32);
        #pragma unroll
        for (int f = 0; f < 8; ++f) {
            s8v b = *(const s8v*)(pb + (size_t)(kk + 4) * 4096 + f * 128);
            acc[f] = __builtin_amdgcn_mfma_f32_16x16x32_bf16(a, b, acc[f], 0, 0, 0);
        }
    }

    if (seg == 0) {
        #pragma unroll
        for (int bh = 0; bh < 2; ++bh) {
            const int j = bn * 32 + bh * 16 + lc;
            const float gi = acc[bh * 4 + 0][0] + bsum[j];
            const float gf = acc[bh * 4 + 1][0] + bsum[128 + j];
            const float gg = acc[bh * 4 + 2][0] + bsum[256 + j];
            const float go = acc[bh * 4 + 3][0] + bsum[384 + j];
            const float cn = sigf(gf) * c_in[j] + sigf(gi) * tanh_fast(gg);
            hs[j] = sigf(go) * tanh_fast(cn);
        }
    }
    __syncthreads();
    if (tid < 128) {
        float a1 = b1[tid];
        #pragma unroll 4
        for (int k = 0; k < 128; ++k) a1 = fmaf(hs[k], W1[tid * 128 + k], a1);
        as[tid] = fmaxf(a1, 0.0f);
    }
    __syncthreads();
    if (tid < 32) {
        float l = b2[tid];
        #pragma unroll 4
        for (int k = 0; k < 128; ++k) l = fmaf(as[k], W2[tid * 128 + k], l);
        l = (l + logf(vmask[tid])) * (1.0f / 3.0f);
        float mx = l;
        #pragma unroll
        for (int o = 16; o >= 1; o >>= 1) mx = fmaxf(mx, __shfl_xor(mx, o, 32));
        const float e = __expf(l - mx);
        float s = e;
        #pragma unroll
        for (int o = 16; o >= 1; o >>= 1) s += __shfl_xor(s, o, 32);
        out[tid] = e / s;
    }
}

extern "C" void kernel_launch(void* const* d_in, const int* in_sizes, int n_in,
                              void* d_out, int out_size, void* d_ws, size_t ws_size,
                              hipStream_t stream)
{
    const int*   node_types = (const int*)  d_in[0];
    const float* node_args  = (const float*)d_in[1];
    const float* vmask      = (const float*)d_in[2];
    const float* emb        = (const float*)d_in[3];
    const float* Wih        = (const float*)d_in[4];
    const float* Whh        = (const float*)d_in[5];
    const float* bih        = (const float*)d_in[6];
    const float* bhh        = (const float*)d_in[7];
    const float* W1         = (const float*)d_in[8];
    const float* b1         = (const float*)d_in[9];
    const float* W2         = (const float*)d_in[10];
    const float* b2         = (const float*)d_in[11];

    char* w = (char*)d_ws;
    ushort* xall  = (ushort*)(w);                 // 65536*128*2 = 16,777,216
    ushort* Bpack = (ushort*)(w + 16777216);      // 393,216
    float*  bsum  = (float*) (w + 17170432);      // 2,048
    ushort* hA    = (ushort*)(w + 17172480);      // 32768*128*2 = 8,388,608
    float*  cA    = (float*) (w + 25561088);      // 16384*128*4 = 8,388,608
    ushort* hB    = (ushort*)(w + 33949696);      // 16384*128*2 = 4,194,304
    float*  cB    = (float*) (w + 38144000);      // 8192*128*4  = 4,194,304

    prepass<<<4096, 256, 0, stream>>>(node_types, node_args, emb,
                                      Wih, Whh, bih, bhh, Bpack, bsum, xall);

    // levels 15..9, single-level kernels, ping-pong A/B (lvl15 -> A)
    const ushort* h_prev = hB;  // dummy (unread at leaf)
    const float*  c_prev = cB;
    for (int lvl = DEPTH - 1; lvl >= 9; --lvl) {
        const int n_l = 1 << lvl;
        const int start = n_l - 1;
        const int pi = (DEPTH - 1 - lvl) & 1;
        ushort* ho = pi ? hB : hA;
        float*  co = pi ? cB : cA;
        dim3 grid(n_l / 64, 4);
        level_gemm<<<grid, 256, 0, stream>>>(
            xall, Bpack, bsum, h_prev, c_prev, ho, co,
            start, n_l, (lvl == DEPTH - 1) ? 0 : 1);
        h_prev = ho; c_prev = co;
    }
    // lvl9 output is in A. Pairs: (C=8,P=7) A->B, (6,5) B->A, (4,3) A->B, (2,1) B->A
    pair_gemm<<<4, 512, 0, stream>>>(xall, Bpack, bsum, hA, cA, hB, cB, 255, 127, 128);
    pair_gemm<<<1, 512, 0, stream>>>(xall, Bpack, bsum, hB, cB, hA, cA,  63,  31,  32);
    pair_gemm<<<1, 512, 0, stream>>>(xall, Bpack, bsum, hA, cA, hB, cB,  15,   7,   8);
    pair_gemm<<<1, 512, 0, stream>>>(xall, Bpack, bsum, hB, cB, hA, cA,   3,   1,   2);

    root_and_head<<<1, 256, 0, stream>>>(
        node_types, node_args, emb, Bpack, bsum, hA, cA,
        W1, b1, W2, b2, vmask, (float*)d_out);
}

// Round 7
// 201.104 us; speedup vs baseline: 5.2250x; 1.0982x over previous
//
#include <hip/hip_runtime.h>
#include <hip/hip_bf16.h>

#define DEPTH 16

typedef __attribute__((ext_vector_type(8))) short s8v;   // 8 x bf16
typedef __attribute__((ext_vector_type(4))) float f32x4; // MFMA acc

__device__ __forceinline__ float sigf(float x) { return 1.0f / (1.0f + __expf(-x)); }
__device__ __forceinline__ float tanh_fast(float x) { return 1.0f - 2.0f / (1.0f + __expf(2.0f * x)); }
__device__ __forceinline__ ushort f2bf(float f) {
    union { __hip_bfloat16 b; ushort u; } v; v.b = __float2bfloat16(f); return v.u;
}
__device__ __forceinline__ float bf2f(ushort u) {
    union { float f; unsigned int i; } v; v.i = ((unsigned int)u) << 16; return v.f;
}

// ---------------- prepass: pack weights + fused bias + bf16 embedding gather ----------------
// Bpack: (((bn*12 + kk)*4 + seg)*128 + nl)*8 + t, col order nl -> g=(nl>>4)&3,
// j = bn*32 + (nl>>6)*16 + (nl&15)  => after MFMA each lane holds all 4 gates of one j.
__global__ __launch_bounds__(256) void prepass(
    const int* __restrict__ nt, const float* __restrict__ na,
    const float* __restrict__ emb,
    const float* __restrict__ Wih, const float* __restrict__ Whh,
    const float* __restrict__ bih, const float* __restrict__ bhh,
    ushort* __restrict__ Bpack, float* __restrict__ bsum,
    ushort* __restrict__ xall)
{
    const int gid = blockIdx.x * 256 + threadIdx.x;
    if (gid < 24576) {
        const int nl  = gid & 127;
        const int seg = (gid >> 7) & 3;
        const int rest = gid >> 9;
        const int kk = rest % 12;
        const int bn = rest / 12;
        const int g  = (nl >> 4) & 3;
        const int j  = bn * 32 + ((nl >> 6) << 4) + (nl & 15);
        const int row = g * 256 + j;
        const int k = kk * 32 + seg * 8;
        const float* src = (k < 128) ? (Wih + (size_t)row * 128 + k)
                                     : (Whh + (size_t)row * 256 + (k - 128));
        float4 w0 = *(const float4*)(src);
        float4 w1 = *(const float4*)(src + 4);
        ushort o[8] = { f2bf(w0.x), f2bf(w0.y), f2bf(w0.z), f2bf(w0.w),
                        f2bf(w1.x), f2bf(w1.y), f2bf(w1.z), f2bf(w1.w) };
        *(s8v*)(Bpack + (size_t)gid * 8) = *(const s8v*)o;
    }
    if (gid < 512) {
        const int row = (gid >> 7) * 256 + (gid & 127);
        bsum[gid] = bih[row] + bhh[row];
    }
    const int node = gid >> 4;
    const int run  = gid & 15;
    if (node < 65535) {
        const int ty = nt[node];
        const float* src = emb + (size_t)ty * 128 + run * 8;
        float4 w0 = *(const float4*)src;
        float4 w1 = *(const float4*)(src + 4);
        if (run == 15 && (ty == 1 || ty == 2)) w1.w = na[node];
        ushort o[8] = { f2bf(w0.x), f2bf(w0.y), f2bf(w0.z), f2bf(w0.w),
                        f2bf(w1.x), f2bf(w1.y), f2bf(w1.z), f2bf(w1.w) };
        *(s8v*)(xall + (size_t)node * 128 + run * 8) = *(const s8v*)o;
    }
}

// ---------------- two-level pair kernel (any level size) ----------------
// Block b: parents [32b,32b+32) of level P, children [64b,64b+64) of level C=P+1
// (stage 1 -> LDS), grandchildren (level C+1) read from global when has_h.
__global__ __launch_bounds__(512) void pair_gemm(
    const ushort* __restrict__ xall,
    const ushort* __restrict__ Bpack, const float* __restrict__ bsum,
    const ushort* __restrict__ h_in, const float* __restrict__ c_in,  // level C+1: h full, c compact
    ushort* __restrict__ h_out, float* __restrict__ c_out,            // level P: h full, c compact
    int startC, int startP, int nP, int has_h)
{
    __shared__ __align__(16) ushort hC[64][136];
    __shared__ float cC[32][132];

    const int tid  = threadIdx.x;
    const int lane = tid & 63;
    const int wave = tid >> 6;
    const int lc = lane & 15, seg = lane >> 4;
    const int koff = seg * 8;
    const int nC = 2 * nP;
    const int b = blockIdx.x;

    // ===== stage 1: level C (children), M=64, N=512 =====
    {
        const int wm2 = wave >> 2;
        const int bn  = wave & 3;
        const ushort* px[2];
        const ushort* ph[2][2];
        #pragma unroll
        for (int mi = 0; mi < 2; ++mi) {
            int mloc = wm2 * 32 + mi * 16 + lc;
            int cg = 64 * b + mloc;
            int cgc = cg < nC ? cg : nC - 1;
            px[mi]    = xall + (size_t)(startC + cgc) * 128 + koff;
            ph[mi][0] = h_in + (size_t)(2 * cgc) * 128 + koff;
            ph[mi][1] = h_in + (size_t)(2 * cgc + 1) * 128 + koff;
        }
        const ushort* pb = Bpack + (size_t)bn * 49152 + (size_t)seg * 1024
                                 + (size_t)lc * 8;

        f32x4 acc[2][8];
        #pragma unroll
        for (int mi = 0; mi < 2; ++mi)
            #pragma unroll
            for (int f = 0; f < 8; ++f) acc[mi][f] = (f32x4){0.f, 0.f, 0.f, 0.f};

        #pragma unroll
        for (int kk = 0; kk < 4; ++kk) {
            s8v a0 = *(const s8v*)(px[0] + kk * 32);
            s8v a1 = *(const s8v*)(px[1] + kk * 32);
            #pragma unroll
            for (int f = 0; f < 8; ++f) {
                s8v bb = *(const s8v*)(pb + (size_t)kk * 4096 + f * 128);
                acc[0][f] = __builtin_amdgcn_mfma_f32_16x16x32_bf16(a0, bb, acc[0][f], 0, 0, 0);
                acc[1][f] = __builtin_amdgcn_mfma_f32_16x16x32_bf16(a1, bb, acc[1][f], 0, 0, 0);
            }
        }
        if (has_h) {
            #pragma unroll
            for (int kk = 0; kk < 8; ++kk) {
                const int hi = kk >> 2, off = (kk & 3) * 32;
                s8v a0 = *(const s8v*)(ph[0][hi] + off);
                s8v a1 = *(const s8v*)(ph[1][hi] + off);
                #pragma unroll
                for (int f = 0; f < 8; ++f) {
                    s8v bb = *(const s8v*)(pb + (size_t)(kk + 4) * 4096 + f * 128);
                    acc[0][f] = __builtin_amdgcn_mfma_f32_16x16x32_bf16(a0, bb, acc[0][f], 0, 0, 0);
                    acc[1][f] = __builtin_amdgcn_mfma_f32_16x16x32_bf16(a1, bb, acc[1][f], 0, 0, 0);
                }
            }
        }
        // epilogue 1 -> LDS
        #pragma unroll
        for (int bh = 0; bh < 2; ++bh) {
            const int j = bn * 32 + bh * 16 + lc;
            const float bi = bsum[j];
            const float bf = bsum[128 + j];
            const float bg = bsum[256 + j];
            const float bo = bsum[384 + j];
            #pragma unroll
            for (int mi = 0; mi < 2; ++mi) {
                #pragma unroll
                for (int r = 0; r < 4; ++r) {
                    const int mloc = wm2 * 32 + mi * 16 + seg * 4 + r;
                    const int cg = 64 * b + mloc;
                    if (cg < nC) {
                        const float gi = acc[mi][bh * 4 + 0][r] + bi;
                        const float gf = acc[mi][bh * 4 + 1][r] + bf;
                        const float gg = acc[mi][bh * 4 + 2][r] + bg;
                        const float go = acc[mi][bh * 4 + 3][r] + bo;
                        const float c0 = has_h ? c_in[(size_t)cg * 128 + j] : 0.0f;
                        const float cn = sigf(gf) * c0 + sigf(gi) * tanh_fast(gg);
                        const float hn = sigf(go) * tanh_fast(cn);
                        hC[mloc][j] = f2bf(hn);
                        if (!(mloc & 1)) cC[mloc >> 1][j] = cn;
                    }
                }
            }
        }
    }
    __syncthreads();

    // ===== stage 2: level P (parents), M=32, N=512 =====
    {
        const int bn = wave >> 1;
        const int wn = wave & 1;
        const ushort* px[2];
        int mcl[2];
        #pragma unroll
        for (int mi = 0; mi < 2; ++mi) {
            int m = mi * 16 + lc;
            int mPg = 32 * b + m;
            int mc = mPg < nP ? mPg : nP - 1;
            mcl[mi] = mc - 32 * b;   // clamped local parent row
            px[mi] = xall + (size_t)(startP + mc) * 128 + koff;
        }
        const ushort* pb = Bpack + (size_t)bn * 49152 + (size_t)seg * 1024
                                 + (size_t)(wn * 64 + lc) * 8;

        f32x4 acc[2][4];
        #pragma unroll
        for (int mi = 0; mi < 2; ++mi)
            #pragma unroll
            for (int f = 0; f < 4; ++f) acc[mi][f] = (f32x4){0.f, 0.f, 0.f, 0.f};

        #pragma unroll
        for (int kk = 0; kk < 4; ++kk) {
            s8v a0 = *(const s8v*)(px[0] + kk * 32);
            s8v a1 = *(const s8v*)(px[1] + kk * 32);
            #pragma unroll
            for (int f = 0; f < 4; ++f) {
                s8v bb = *(const s8v*)(pb + (size_t)kk * 4096 + f * 128);
                acc[0][f] = __builtin_amdgcn_mfma_f32_16x16x32_bf16(a0, bb, acc[0][f], 0, 0, 0);
                acc[1][f] = __builtin_amdgcn_mfma_f32_16x16x32_bf16(a1, bb, acc[1][f], 0, 0, 0);
            }
        }
        #pragma unroll
        for (int kk = 0; kk < 8; ++kk) {
            const int hi = kk >> 2, off = (kk & 3) * 32;
            s8v a0 = *(const s8v*)(&hC[2 * mcl[0] + hi][off + koff]);
            s8v a1 = *(const s8v*)(&hC[2 * mcl[1] + hi][off + koff]);
            #pragma unroll
            for (int f = 0; f < 4; ++f) {
                s8v bb = *(const s8v*)(pb + (size_t)(kk + 4) * 4096 + f * 128);
                acc[0][f] = __builtin_amdgcn_mfma_f32_16x16x32_bf16(a0, bb, acc[0][f], 0, 0, 0);
                acc[1][f] = __builtin_amdgcn_mfma_f32_16x16x32_bf16(a1, bb, acc[1][f], 0, 0, 0);
            }
        }

        const int j = bn * 32 + wn * 16 + lc;
        const float bi = bsum[j];
        const float bf = bsum[128 + j];
        const float bg = bsum[256 + j];
        const float bo = bsum[384 + j];
        #pragma unroll
        for (int mi = 0; mi < 2; ++mi) {
            #pragma unroll
            for (int r = 0; r < 4; ++r) {
                const int m = mi * 16 + seg * 4 + r;
                const int mPg = 32 * b + m;
                if (mPg < nP) {
                    const float gi = acc[mi][0][r] + bi;
                    const float gf = acc[mi][1][r] + bf;
                    const float gg = acc[mi][2][r] + bg;
                    const float go = acc[mi][3][r] + bo;
                    const float c0 = cC[m][j];
                    const float cn = sigf(gf) * c0 + sigf(gi) * tanh_fast(gg);
                    const float hn = sigf(go) * tanh_fast(cn);
                    h_out[(size_t)mPg * 128 + j] = f2bf(hn);
                    if (!(mPg & 1)) c_out[(size_t)(mPg >> 1) * 128 + j] = cn;
                }
            }
        }
    }
}

// ---------------- tail: levels 5..0 + head in one block ----------------
// One stage = one level (nP nodes <= 32), M=32 tile clamped, N=512, 8 waves.
__device__ __forceinline__ void tail_stage(
    int nP, int startP, int first,
    const ushort* __restrict__ xall,
    const ushort* __restrict__ Bpack, const float* __restrict__ bsum,
    const ushort* __restrict__ hg, const float* __restrict__ cg,   // global child (first)
    ushort (*hin)[136], float (*cin)[132],                          // LDS child (!first)
    ushort (*hout)[136], float (*cout)[132])
{
    const int tid  = threadIdx.x;
    const int lane = tid & 63;
    const int wave = tid >> 6;
    const int bn = wave >> 1, wn = wave & 1;
    const int lc = lane & 15, seg = lane >> 4;
    const int koff = seg * 8;

    const ushort* px[2];
    int mcl[2];
    #pragma unroll
    for (int mi = 0; mi < 2; ++mi) {
        int m = mi * 16 + lc;
        int mc = m < nP ? m : nP - 1;
        mcl[mi] = mc;
        px[mi] = xall + (size_t)(startP + mc) * 128 + koff;
    }
    const ushort* pb = Bpack + (size_t)bn * 49152 + (size_t)seg * 1024
                             + (size_t)(wn * 64 + lc) * 8;

    f32x4 acc[2][4];
    #pragma unroll
    for (int mi = 0; mi < 2; ++mi)
        #pragma unroll
        for (int f = 0; f < 4; ++f) acc[mi][f] = (f32x4){0.f, 0.f, 0.f, 0.f};

    #pragma unroll
    for (int kk = 0; kk < 4; ++kk) {
        s8v a0 = *(const s8v*)(px[0] + kk * 32);
        s8v a1 = *(const s8v*)(px[1] + kk * 32);
        #pragma unroll
        for (int f = 0; f < 4; ++f) {
            s8v bb = *(const s8v*)(pb + (size_t)kk * 4096 + f * 128);
            acc[0][f] = __builtin_amdgcn_mfma_f32_16x16x32_bf16(a0, bb, acc[0][f], 0, 0, 0);
            acc[1][f] = __builtin_amdgcn_mfma_f32_16x16x32_bf16(a1, bb, acc[1][f], 0, 0, 0);
        }
    }
    #pragma unroll
    for (int kk = 0; kk < 8; ++kk) {
        const int hi = kk >> 2, off = (kk & 3) * 32;
        s8v a0, a1;
        if (first) {
            a0 = *(const s8v*)(hg + (size_t)(2 * mcl[0] + hi) * 128 + koff + off);
            a1 = *(const s8v*)(hg + (size_t)(2 * mcl[1] + hi) * 128 + koff + off);
        } else {
            a0 = *(const s8v*)(&hin[2 * mcl[0] + hi][koff + off]);
            a1 = *(const s8v*)(&hin[2 * mcl[1] + hi][koff + off]);
        }
        #pragma unroll
        for (int f = 0; f < 4; ++f) {
            s8v bb = *(const s8v*)(pb + (size_t)(kk + 4) * 4096 + f * 128);
            acc[0][f] = __builtin_amdgcn_mfma_f32_16x16x32_bf16(a0, bb, acc[0][f], 0, 0, 0);
            acc[1][f] = __builtin_amdgcn_mfma_f32_16x16x32_bf16(a1, bb, acc[1][f], 0, 0, 0);
        }
    }

    const int j = bn * 32 + wn * 16 + lc;
    const float bi = bsum[j];
    const float bf = bsum[128 + j];
    const float bg = bsum[256 + j];
    const float bo = bsum[384 + j];
    #pragma unroll
    for (int mi = 0; mi < 2; ++mi) {
        #pragma unroll
        for (int r = 0; r < 4; ++r) {
            const int m = mi * 16 + seg * 4 + r;
            if (m < nP) {
                const float gi = acc[mi][0][r] + bi;
                const float gf = acc[mi][1][r] + bf;
                const float gg = acc[mi][2][r] + bg;
                const float go = acc[mi][3][r] + bo;
                const float c0 = first ? cg[(size_t)m * 128 + j] : cin[m][j];
                const float cn = sigf(gf) * c0 + sigf(gi) * tanh_fast(gg);
                const float hn = sigf(go) * tanh_fast(cn);
                hout[m][j] = f2bf(hn);
                if (!(m & 1)) cout[m >> 1][j] = cn;
            }
        }
    }
}

__global__ __launch_bounds__(512) void tail_kernel(
    const ushort* __restrict__ xall,
    const ushort* __restrict__ Bpack, const float* __restrict__ bsum,
    const ushort* __restrict__ h6, const float* __restrict__ c6,
    const float* __restrict__ W1, const float* __restrict__ b1,
    const float* __restrict__ W2, const float* __restrict__ b2,
    const float* __restrict__ vmask, float* __restrict__ out)
{
    __shared__ __align__(16) ushort hT[2][32][136];
    __shared__ float cT[2][16][132];
    __shared__ float hs[128];
    __shared__ float as[128];
    const int tid = threadIdx.x;

    tail_stage(32, 31, 1, xall, Bpack, bsum, h6, c6, nullptr, nullptr, hT[0], cT[0]);
    __syncthreads();
    tail_stage(16, 15, 0, xall, Bpack, bsum, nullptr, nullptr, hT[0], cT[0], hT[1], cT[1]);
    __syncthreads();
    tail_stage(8, 7, 0, xall, Bpack, bsum, nullptr, nullptr, hT[1], cT[1], hT[0], cT[0]);
    __syncthreads();
    tail_stage(4, 3, 0, xall, Bpack, bsum, nullptr, nullptr, hT[0], cT[0], hT[1], cT[1]);
    __syncthreads();
    tail_stage(2, 1, 0, xall, Bpack, bsum, nullptr, nullptr, hT[1], cT[1], hT[0], cT[0]);
    __syncthreads();
    tail_stage(1, 0, 0, xall, Bpack, bsum, nullptr, nullptr, hT[0], cT[0], hT[1], cT[1]);
    __syncthreads();

    // head: root h in hT[1][0][*]
    if (tid < 128) hs[tid] = bf2f(hT[1][0][tid]);
    __syncthreads();
    if (tid < 128) {
        float a1 = b1[tid];
        #pragma unroll 4
        for (int k = 0; k < 128; ++k) a1 = fmaf(hs[k], W1[tid * 128 + k], a1);
        as[tid] = fmaxf(a1, 0.0f);
    }
    __syncthreads();
    if (tid < 32) {
        float l = b2[tid];
        #pragma unroll 4
        for (int k = 0; k < 128; ++k) l = fmaf(as[k], W2[tid * 128 + k], l);
        l = (l + logf(vmask[tid])) * (1.0f / 3.0f);
        float mx = l;
        #pragma unroll
        for (int o = 16; o >= 1; o >>= 1) mx = fmaxf(mx, __shfl_xor(mx, o, 32));
        const float e = __expf(l - mx);
        float s = e;
        #pragma unroll
        for (int o = 16; o >= 1; o >>= 1) s += __shfl_xor(s, o, 32);
        out[tid] = e / s;
    }
}

extern "C" void kernel_launch(void* const* d_in, const int* in_sizes, int n_in,
                              void* d_out, int out_size, void* d_ws, size_t ws_size,
                              hipStream_t stream)
{
    const int*   node_types = (const int*)  d_in[0];
    const float* node_args  = (const float*)d_in[1];
    const float* vmask      = (const float*)d_in[2];
    const float* emb        = (const float*)d_in[3];
    const float* Wih        = (const float*)d_in[4];
    const float* Whh        = (const float*)d_in[5];
    const float* bih        = (const float*)d_in[6];
    const float* bhh        = (const float*)d_in[7];
    const float* W1         = (const float*)d_in[8];
    const float* b1         = (const float*)d_in[9];
    const float* W2         = (const float*)d_in[10];
    const float* b2         = (const float*)d_in[11];

    char* w = (char*)d_ws;
    ushort* xall  = (ushort*)(w);                 // 65536*128*2 = 16,777,216
    ushort* Bpack = (ushort*)(w + 16777216);      // 393,216
    float*  bsum  = (float*) (w + 17170432);      // 2,048
    ushort* hA    = (ushort*)(w + 17172480);      // up to 16384*128*2 = 4,194,304 (pad region 8.4MB)
    float*  cA    = (float*) (w + 25561088);      // up to 8192*128*4 = 4,194,304 (pad region 8.4MB)
    ushort* hB    = (ushort*)(w + 33949696);      // 4096*128*2 = 1,048,576 (pad 4.2MB)
    float*  cB    = (float*) (w + 38144000);      // 2048*128*4 = 1,048,576 (pad 4.2MB)

    prepass<<<4096, 256, 0, stream>>>(node_types, node_args, emb,
                                      Wih, Whh, bih, bhh, Bpack, bsum, xall);

    // pairs: (C,P) = (15,14) leaf -> A, (13,12) A->B, (11,10) B->A, (9,8) A->B, (7,6) B->A
    pair_gemm<<<512, 512, 0, stream>>>(xall, Bpack, bsum, hB, cB, hA, cA, 32767, 16383, 16384, 0);
    pair_gemm<<<128, 512, 0, stream>>>(xall, Bpack, bsum, hA, cA, hB, cB,  8191,  4095,  4096, 1);
    pair_gemm<<< 32, 512, 0, stream>>>(xall, Bpack, bsum, hB, cB, hA, cA,  2047,  1023,  1024, 1);
    pair_gemm<<<  8, 512, 0, stream>>>(xall, Bpack, bsum, hA, cA, hB, cB,   511,   255,   256, 1);
    pair_gemm<<<  2, 512, 0, stream>>>(xall, Bpack, bsum, hB, cB, hA, cA,   127,    63,    64, 1);

    // tail: levels 5..0 + head (reads level-6 h/c from A)
    tail_kernel<<<1, 512, 0, stream>>>(xall, Bpack, bsum, hA, cA,
                                       W1, b1, W2, b2, vmask, (float*)d_out);
}